// Round 7
// baseline (561.952 us; speedup 1.0000x reference)
//
#include <hip/hip_runtime.h>
#include <hip/hip_bf16.h>

typedef __hip_bfloat16 bf16;
typedef short bf16x8 __attribute__((ext_vector_type(8)));
typedef float f32x4  __attribute__((ext_vector_type(4)));

#define ROWS 53176    // B * L_TOTAL
#define LTOT 13294

__device__ __forceinline__ float b2f(bf16 v) { return __bfloat162float(v); }

__device__ __forceinline__ void gl2lds16(const void* g, void* l) {
    __builtin_amdgcn_global_load_lds(
        (const __attribute__((address_space(1))) unsigned*)g,
        (__attribute__((address_space(3))) unsigned*)l, 16, 0, 0);
}

// ============ narrow MFMA GEMM: 128x128 tile, transposed-acc epilogue ============
template<bool RELU>
__global__ __launch_bounds__(256)
void mfma_gemm_n(const bf16* __restrict__ A, const bf16* __restrict__ Bt,
                 const float* __restrict__ bias, bf16* __restrict__ C,
                 int M, int N, int K)
{
    __shared__ __align__(16) short As[128 * 32];
    __shared__ __align__(16) short Bs[128 * 32];
    const int tid  = threadIdx.x;
    const int wave = tid >> 6, lane = tid & 63;
    const int m0 = blockIdx.y * 128, n0 = blockIdx.x * 128;
    const int lrow = lane >> 2, lcol = lane & 3;
    const int quad = lane >> 4;

    f32x4 acc[4][4];
#pragma unroll
    for (int i = 0; i < 4; ++i)
#pragma unroll
        for (int j = 0; j < 4; ++j) acc[i][j] = (f32x4){0.f, 0.f, 0.f, 0.f};

    const int wM = (wave >> 1) * 64, wN = (wave & 1) * 64;
    const int foff = (lane & 15) * 32 + quad * 8;

    for (int kk = 0; kk < K; kk += 32) {
#pragma unroll
        for (int q = 0; q < 2; ++q) {
            int rbase = wave * 32 + q * 16;
            int row = rbase + lrow;
            gl2lds16(A  + (size_t)(m0 + row) * K + kk + lcol * 8, &As[rbase * 32]);
            gl2lds16(Bt + (size_t)(n0 + row) * K + kk + lcol * 8, &Bs[rbase * 32]);
        }
        __syncthreads();
        bf16x8 af[4], bfr[4];
#pragma unroll
        for (int i = 0; i < 4; ++i)
            af[i] = *(const bf16x8*)&As[(wM + i * 16) * 32 + foff];
#pragma unroll
        for (int j = 0; j < 4; ++j)
            bfr[j] = *(const bf16x8*)&Bs[(wN + j * 16) * 32 + foff];
#pragma unroll
        for (int i = 0; i < 4; ++i)
#pragma unroll
            for (int j = 0; j < 4; ++j)
                acc[i][j] = __builtin_amdgcn_mfma_f32_16x16x32_bf16(bfr[j], af[i], acc[i][j], 0, 0, 0);
        __syncthreads();
    }

    float4 b4[4];
#pragma unroll
    for (int j = 0; j < 4; ++j)
        b4[j] = *(const float4*)&bias[n0 + wN + j * 16 + quad * 4];

#pragma unroll
    for (int i = 0; i < 4; ++i) {
        int gm = m0 + wM + i * 16 + (lane & 15);
        if (gm >= M) continue;
#pragma unroll
        for (int j = 0; j < 4; ++j) {
            int gn = n0 + wN + j * 16 + quad * 4;
            union { bf16 h[4]; uint2 u2; } pk;
#pragma unroll
            for (int r = 0; r < 4; ++r) {
                float v = acc[i][j][r] + ((const float*)&b4[j])[r];
                if (RELU) v = fmaxf(v, 0.f);
                pk.h[r] = __float2bfloat16(v);
            }
            *(uint2*)&C[(size_t)gm * N + gn] = pk.u2;
        }
    }
}

// ============ wide MFMA GEMM with fused LayerNorm: 128x256 tile, 512 thr ============
// out = LN( A[M,K] @ Bt[256,K]^T + bias + res(bf16) ) ; out bf16
__global__ __launch_bounds__(512)
void mfma_gemm_ln(const bf16* __restrict__ A, const bf16* __restrict__ Bt,
                  const float* __restrict__ bias, const bf16* __restrict__ res,
                  bf16* __restrict__ C, const float* __restrict__ gam,
                  const float* __restrict__ bet, int M, int K)
{
    __shared__ __align__(16) short As[128 * 32];
    __shared__ __align__(16) short Bs[256 * 32];
    __shared__ float rsum[128], rsq[128];
    const int tid  = threadIdx.x;
    const int wave = tid >> 6, lane = tid & 63;
    const int m0 = blockIdx.x * 128;
    const int lrow = lane >> 2, lcol = lane & 3;
    const int quad = lane >> 4;
    if (tid < 128) { rsum[tid] = 0.f; rsq[tid] = 0.f; }

    f32x4 acc[4][4];
#pragma unroll
    for (int i = 0; i < 4; ++i)
#pragma unroll
        for (int j = 0; j < 4; ++j) acc[i][j] = (f32x4){0.f, 0.f, 0.f, 0.f};

    const int wM = (wave >> 2) * 64, wN = (wave & 3) * 64;
    const int foff = (lane & 15) * 32 + quad * 8;

    for (int kk = 0; kk < K; kk += 32) {
#pragma unroll
        for (int q = 0; q < 3; ++q) {
            int r = wave * 48 + q * 16;
            if (r < 128) {
                gl2lds16(A + (size_t)(m0 + r + lrow) * K + kk + lcol * 8, &As[r * 32]);
            } else {
                int rr = r - 128;
                gl2lds16(Bt + (size_t)(rr + lrow) * K + kk + lcol * 8, &Bs[rr * 32]);
            }
        }
        __syncthreads();
        bf16x8 af[4], bfr[4];
#pragma unroll
        for (int i = 0; i < 4; ++i)
            af[i] = *(const bf16x8*)&As[(wM + i * 16) * 32 + foff];
#pragma unroll
        for (int j = 0; j < 4; ++j)
            bfr[j] = *(const bf16x8*)&Bs[(wN + j * 16) * 32 + foff];
#pragma unroll
        for (int i = 0; i < 4; ++i)
#pragma unroll
            for (int j = 0; j < 4; ++j)
                acc[i][j] = __builtin_amdgcn_mfma_f32_16x16x32_bf16(bfr[j], af[i], acc[i][j], 0, 0, 0);
        __syncthreads();
    }

    float4 b4[4], g4[4], be4[4];
#pragma unroll
    for (int j = 0; j < 4; ++j) {
        int gn = wN + j * 16 + quad * 4;
        b4[j]  = *(const float4*)&bias[gn];
        g4[j]  = *(const float4*)&gam[gn];
        be4[j] = *(const float4*)&bet[gn];
    }

    float lsum[4], lsq[4];
#pragma unroll
    for (int i = 0; i < 4; ++i) {
        int gm = m0 + wM + i * 16 + (lane & 15);
        lsum[i] = 0.f; lsq[i] = 0.f;
#pragma unroll
        for (int j = 0; j < 4; ++j) {
            int gn = wN + j * 16 + quad * 4;
            float r4[4] = {0.f, 0.f, 0.f, 0.f};
            if (gm < M) {
                uint2 ru = *(const uint2*)&res[(size_t)gm * 256 + gn];
                const bf16* rh = (const bf16*)&ru;
#pragma unroll
                for (int r = 0; r < 4; ++r) r4[r] = b2f(rh[r]);
            }
#pragma unroll
            for (int r = 0; r < 4; ++r) {
                float v = acc[i][j][r] + ((const float*)&b4[j])[r] + r4[r];
                acc[i][j][r] = v;
                lsum[i] += v;
                lsq[i]  += v * v;
            }
        }
#pragma unroll
        for (int mask = 16; mask <= 32; mask <<= 1) {
            lsum[i] += __shfl_xor(lsum[i], mask);
            lsq[i]  += __shfl_xor(lsq[i], mask);
        }
    }
    if (quad == 0) {
#pragma unroll
        for (int i = 0; i < 4; ++i) {
            atomicAdd(&rsum[wM + i * 16 + (lane & 15)], lsum[i]);
            atomicAdd(&rsq [wM + i * 16 + (lane & 15)], lsq[i]);
        }
    }
    __syncthreads();

#pragma unroll
    for (int i = 0; i < 4; ++i) {
        int lr = wM + i * 16 + (lane & 15);
        int gm = m0 + lr;
        if (gm >= M) continue;
        float mean = rsum[lr] * (1.f / 256.f);
        float var  = rsq[lr] * (1.f / 256.f) - mean * mean;
        float rstd = rsqrtf(fmaxf(var, 0.f) + 1e-5f);
#pragma unroll
        for (int j = 0; j < 4; ++j) {
            int gn = wN + j * 16 + quad * 4;
            union { bf16 h[4]; uint2 u2; } pk;
#pragma unroll
            for (int r = 0; r < 4; ++r)
                pk.h[r] = __float2bfloat16((acc[i][j][r] - mean) * rstd *
                          ((const float*)&g4[j])[r] + ((const float*)&be4[j])[r]);
            *(uint2*)&C[(size_t)gm * 256 + gn] = pk.u2;
        }
    }
}

// ============ fused FFN: out = LN( relu(x@W1+b1)@W2 + b2 + x ) ============
// 64-row blocks; x-tile persistent in LDS; h never touches HBM.
__global__ __launch_bounds__(256)
void ffn_fused(const bf16* __restrict__ x, const bf16* __restrict__ W1t,
               const float* __restrict__ b1, const bf16* __restrict__ W2t,
               const float* __restrict__ b2v, float* __restrict__ out,
               const float* __restrict__ gam, const float* __restrict__ bet, int M)
{
    __shared__ __align__(16) short Xs[64 * 264];   // +8 pad: 2-way banks
    __shared__ __align__(16) short Hs[64 * 136];   // +8 pad
    __shared__ __align__(16) short Bs[256 * 32];   // weight staging
    __shared__ float rsum[64], rsq[64];
    const int tid = threadIdx.x, wave = tid >> 6, lane = tid & 63;
    const int quad = lane >> 4;
    const int lrow = lane >> 2, lcol = lane & 3;
    const int m0 = blockIdx.x * 64;
    const int foff = (lane & 15) * 32 + quad * 8;
    if (tid < 64) { rsum[tid] = 0.f; rsq[tid] = 0.f; }

    // load x tile (64 x 256 bf16 = 64 x 32 int4-chunks) into padded LDS
    for (int c = tid; c < 64 * 32; c += 256) {
        int r = c >> 5, cc = c & 31;
        int gr = m0 + r; if (gr >= M) gr = M - 1;   // clamp tail rows
        int4 d = *(const int4*)(x + (size_t)gr * 256 + cc * 8);
        *(int4*)&Xs[r * 264 + cc * 8] = d;
    }

    f32x4 acc2[2][8];
#pragma unroll
    for (int i = 0; i < 2; ++i)
#pragma unroll
        for (int j = 0; j < 8; ++j) acc2[i][j] = (f32x4){0.f, 0.f, 0.f, 0.f};

    const int wM = (wave >> 1) * 32;               // M rows for both stages
    const int wN1 = (wave & 1) * 64;               // stage-1 N (128 chunk)
    const int wN2 = (wave & 1) * 128;              // stage-2 N (256)

    for (int j = 0; j < 8; ++j) {
        // ---- stage 1: Hs = relu(Xs @ W1t[j*128 .. +128][:]) ----
        f32x4 acc1[2][4];
#pragma unroll
        for (int i = 0; i < 2; ++i)
#pragma unroll
            for (int jj = 0; jj < 4; ++jj) acc1[i][jj] = (f32x4){0.f, 0.f, 0.f, 0.f};
        for (int kk = 0; kk < 256; kk += 32) {
            __syncthreads();   // Bs reads from previous iter done (also orders Xs init)
#pragma unroll
            for (int q = 0; q < 2; ++q) {
                int rbase = wave * 32 + q * 16;
                gl2lds16(W1t + (size_t)(j * 128 + rbase + lrow) * 256 + kk + lcol * 8,
                         &Bs[rbase * 32]);
            }
            __syncthreads();
            bf16x8 hf[2], wf[4];
#pragma unroll
            for (int i = 0; i < 2; ++i)
                hf[i] = *(const bf16x8*)&Xs[(wM + i * 16 + (lane & 15)) * 264 + kk + quad * 8];
#pragma unroll
            for (int jj = 0; jj < 4; ++jj)
                wf[jj] = *(const bf16x8*)&Bs[(wN1 + jj * 16) * 32 + foff];
#pragma unroll
            for (int i = 0; i < 2; ++i)
#pragma unroll
                for (int jj = 0; jj < 4; ++jj)
                    acc1[i][jj] = __builtin_amdgcn_mfma_f32_16x16x32_bf16(wf[jj], hf[i], acc1[i][jj], 0, 0, 0);
        }
        // relu + bias -> Hs
#pragma unroll
        for (int i = 0; i < 2; ++i) {
            int m = wM + i * 16 + (lane & 15);
#pragma unroll
            for (int jj = 0; jj < 4; ++jj) {
                int n = wN1 + jj * 16 + quad * 4;
                float4 bb = *(const float4*)&b1[j * 128 + n];
                union { bf16 h[4]; uint2 u; } pk;
#pragma unroll
                for (int r = 0; r < 4; ++r)
                    pk.h[r] = __float2bfloat16(fmaxf(acc1[i][jj][r] + ((const float*)&bb)[r], 0.f));
                *(uint2*)&Hs[m * 136 + n] = pk.u;
            }
        }
        // ---- stage 2: acc2 += Hs @ W2t[:][j*128 .. +128] ----
        for (int kk = 0; kk < 128; kk += 32) {
            __syncthreads();   // first iter: also orders Hs writes before reads
#pragma unroll
            for (int q = 0; q < 4; ++q) {
                int rbase = wave * 64 + q * 16;
                gl2lds16(W2t + (size_t)(rbase + lrow) * 1024 + j * 128 + kk + lcol * 8,
                         &Bs[rbase * 32]);
            }
            __syncthreads();
            bf16x8 hf2[2], wf2[8];
#pragma unroll
            for (int i = 0; i < 2; ++i)
                hf2[i] = *(const bf16x8*)&Hs[(wM + i * 16 + (lane & 15)) * 136 + kk + quad * 8];
#pragma unroll
            for (int jj = 0; jj < 8; ++jj)
                wf2[jj] = *(const bf16x8*)&Bs[(wN2 + jj * 16) * 32 + foff];
#pragma unroll
            for (int i = 0; i < 2; ++i)
#pragma unroll
                for (int jj = 0; jj < 8; ++jj)
                    acc2[i][jj] = __builtin_amdgcn_mfma_f32_16x16x32_bf16(wf2[jj], hf2[i], acc2[i][jj], 0, 0, 0);
        }
    }

    // ---- epilogue: bias + residual (from Xs) + LN ----
    float4 bb[8], gg[8], be[8];
#pragma unroll
    for (int jj = 0; jj < 8; ++jj) {
        int gn = wN2 + jj * 16 + quad * 4;
        bb[jj] = *(const float4*)&b2v[gn];
        gg[jj] = *(const float4*)&gam[gn];
        be[jj] = *(const float4*)&bet[gn];
    }
    float lsum[2], lsq[2];
#pragma unroll
    for (int i = 0; i < 2; ++i) {
        int lr = wM + i * 16 + (lane & 15);
        lsum[i] = 0.f; lsq[i] = 0.f;
#pragma unroll
        for (int jj = 0; jj < 8; ++jj) {
            int gn = wN2 + jj * 16 + quad * 4;
            uint2 ru = *(const uint2*)&Xs[lr * 264 + gn];
            const bf16* rh = (const bf16*)&ru;
#pragma unroll
            for (int r = 0; r < 4; ++r) {
                float v = acc2[i][jj][r] + ((const float*)&bb[jj])[r] + b2f(rh[r]);
                acc2[i][jj][r] = v;
                lsum[i] += v;
                lsq[i]  += v * v;
            }
        }
#pragma unroll
        for (int mask = 16; mask <= 32; mask <<= 1) {
            lsum[i] += __shfl_xor(lsum[i], mask);
            lsq[i]  += __shfl_xor(lsq[i], mask);
        }
    }
    if (quad == 0) {
#pragma unroll
        for (int i = 0; i < 2; ++i) {
            atomicAdd(&rsum[wM + i * 16 + (lane & 15)], lsum[i]);
            atomicAdd(&rsq [wM + i * 16 + (lane & 15)], lsq[i]);
        }
    }
    __syncthreads();
#pragma unroll
    for (int i = 0; i < 2; ++i) {
        int lr = wM + i * 16 + (lane & 15);
        int gm = m0 + lr;
        if (gm >= M) continue;
        float mean = rsum[lr] * (1.f / 256.f);
        float var  = rsq[lr] * (1.f / 256.f) - mean * mean;
        float rstd = rsqrtf(fmaxf(var, 0.f) + 1e-5f);
#pragma unroll
        for (int jj = 0; jj < 8; ++jj) {
            int gn = wN2 + jj * 16 + quad * 4;
            float4 o;
#pragma unroll
            for (int r = 0; r < 4; ++r)
                ((float*)&o)[r] = (acc2[i][jj][r] - mean) * rstd *
                        ((const float*)&gg[jj])[r] + ((const float*)&be[jj])[r];
            *(float4*)&out[(size_t)gm * 256 + gn] = o;
        }
    }
}

// ============ casts ============
__global__ void cast_qs_kernel(const float* __restrict__ s, const float* __restrict__ p,
                               bf16* __restrict__ sb, bf16* __restrict__ qb, int n4)
{
    int i = blockIdx.x * 256 + threadIdx.x;
    if (i >= n4) return;
    float4 sv = ((const float4*)s)[i];
    float4 pv = ((const float4*)p)[i];
    union { bf16 h[4]; uint2 u; } a, b;
    a.h[0] = __float2bfloat16(sv.x); a.h[1] = __float2bfloat16(sv.y);
    a.h[2] = __float2bfloat16(sv.z); a.h[3] = __float2bfloat16(sv.w);
    b.h[0] = __float2bfloat16(sv.x + pv.x); b.h[1] = __float2bfloat16(sv.y + pv.y);
    b.h[2] = __float2bfloat16(sv.z + pv.z); b.h[3] = __float2bfloat16(sv.w + pv.w);
    ((uint2*)sb)[i] = a.u;
    ((uint2*)qb)[i] = b.u;
}

__global__ void wcast_all(const float* __restrict__ Wval, const float* __restrict__ Woff,
                          const float* __restrict__ Wattn, const float* __restrict__ Wout,
                          const float* __restrict__ W1, const float* __restrict__ W2,
                          const float* __restrict__ boff, const float* __restrict__ battn,
                          bf16* __restrict__ Wval_t, bf16* __restrict__ Wcat_t,
                          bf16* __restrict__ Wout_t, bf16* __restrict__ W1_t,
                          bf16* __restrict__ W2_t, float* __restrict__ bcat)
{
    int e = blockIdx.x * 256 + threadIdx.x;
    if (e < 384) bcat[e] = (e < 256) ? boff[e] : battn[e - 256];
    if (e < 65536) {
        int n = e >> 8, k = e & 255;
        Wval_t[e] = __float2bfloat16(Wval[k * 256 + n]);
    } else if (e < 163840) {
        int i = e - 65536; int n = i >> 8, k = i & 255;
        float w = (n < 256) ? Woff[k * 256 + n] : Wattn[k * 128 + (n - 256)];
        Wcat_t[i] = __float2bfloat16(w);
    } else if (e < 229376) {
        int i = e - 163840; int n = i >> 8, k = i & 255;
        Wout_t[i] = __float2bfloat16(Wout[k * 256 + n]);
    } else if (e < 491520) {
        int i = e - 229376; int n = i >> 8, k = i & 255;
        W1_t[i] = __float2bfloat16(W1[k * 1024 + n]);
    } else if (e < 753664) {
        int i = e - 491520; int n = i >> 10, k = i & 1023;
        W2_t[i] = __float2bfloat16(W2[k * 256 + n]);
    }
}

// ============ deformable sampling + fused softmax ============
__global__ __launch_bounds__(256)
void sample_kernel(const bf16* __restrict__ v, const bf16* __restrict__ ocat,
                   const float* __restrict__ ref, bf16* __restrict__ samp)
{
    __shared__ int4 tab[16][33];
    const int tid = threadIdx.x;
    const int grp = tid >> 4, lane = tid & 15;
    const int gidx = blockIdx.x * 16 + grp;
    const int h = gidx & 7, bq = gidx >> 3, b = bq / LTOT;

    {   // phase A: point p = lane; softmax over 16 lanes
        const int p = lane, l = p >> 2, pp = p & 3;
        const int W = (l == 0) ? 100 : (l == 1) ? 50 : (l == 2) ? 25 : 13;
        const int S = (l == 0) ? 0 : (l == 1) ? 10000 : (l == 2) ? 12500 : 13125;
        const float fW = (float)W;
        float rx = ref[(size_t)bq * 8 + l * 2 + 0];
        float ry = ref[(size_t)bq * 8 + l * 2 + 1];
        const bf16* ob = ocat + (size_t)bq * 384;
        float ox = b2f(ob[h * 32 + l * 8 + pp * 2 + 0]);
        float oy = b2f(ob[h * 32 + l * 8 + pp * 2 + 1]);
        float lg = b2f(ob[256 + h * 16 + p]);
        float m = lg;
#pragma unroll
        for (int mask = 1; mask <= 8; mask <<= 1) m = fmaxf(m, __shfl_xor(m, mask));
        float ev = __expf(lg - m);
        float s = ev;
#pragma unroll
        for (int mask = 1; mask <= 8; mask <<= 1) s += __shfl_xor(s, mask);
        float wgt = ev / s;

        float x = (rx + ox / fW) * fW - 0.5f;
        float y = (ry + oy / fW) * fW - 0.5f;
        float x0f = floorf(x), y0f = floorf(y);
        float lx = x - x0f, ly = y - y0f;
        int x0 = (int)x0f, y0 = (int)y0f;
        float tw[4] = {(1.f - lx) * (1.f - ly), lx * (1.f - ly),
                       (1.f - lx) * ly,         lx * ly};
        const int base = (b * LTOT + S) * 512 + h * 64;
        int  o[4]; float w[4];
#pragma unroll
        for (int t = 0; t < 4; ++t) {
            int xi = x0 + (t & 1), yi = y0 + (t >> 1);
            bool ok = (xi >= 0) & (xi < W) & (yi >= 0) & (yi < W);
            o[t] = ok ? base + (yi * W + xi) * 512 : 0;
            w[t] = ok ? wgt * tw[t] : 0.f;
        }
        tab[grp][p * 2 + 0] = make_int4(o[0], __float_as_int(w[0]), o[1], __float_as_int(w[1]));
        tab[grp][p * 2 + 1] = make_int4(o[2], __float_as_int(w[2]), o[3], __float_as_int(w[3]));
    }
    __syncthreads();

    const int lofs = lane * 4;
    const char* vc = (const char*)v;
    float a0 = 0.f, a1 = 0.f;
#pragma unroll 4
    for (int e2 = 0; e2 < 32; ++e2) {
        int4 q = tab[grp][e2];
        unsigned u0 = *(const unsigned*)(vc + (size_t)(unsigned)(q.x + lofs));
        unsigned u1 = *(const unsigned*)(vc + (size_t)(unsigned)(q.z + lofs));
        float w0 = __int_as_float(q.y), w1 = __int_as_float(q.w);
        a0 += w0 * __uint_as_float(u0 << 16);
        a1 += w0 * __uint_as_float(u0 & 0xffff0000u);
        a0 += w1 * __uint_as_float(u1 << 16);
        a1 += w1 * __uint_as_float(u1 & 0xffff0000u);
    }
    union { struct { bf16 a, b; } h2; unsigned u; } r;
    r.h2.a = __float2bfloat16(a0);
    r.h2.b = __float2bfloat16(a1);
    *(unsigned*)((char*)samp + (size_t)gidx * 64 + lane * 4) = r.u;
}

extern "C" void kernel_launch(void* const* d_in, const int* in_sizes, int n_in,
                              void* d_out, int out_size, void* d_ws, size_t ws_size,
                              hipStream_t stream)
{
    const float* src     = (const float*)d_in[0];
    const float* pos     = (const float*)d_in[1];
    const float* ref     = (const float*)d_in[2];
    const float* W_off   = (const float*)d_in[5];
    const float* b_off   = (const float*)d_in[6];
    const float* W_attn  = (const float*)d_in[7];
    const float* b_attn  = (const float*)d_in[8];
    const float* W_val   = (const float*)d_in[9];
    const float* b_val   = (const float*)d_in[10];
    const float* W_out   = (const float*)d_in[11];
    const float* b_out   = (const float*)d_in[12];
    const float* ln_sa_g = (const float*)d_in[13];
    const float* ln_sa_b = (const float*)d_in[14];
    const float* W1      = (const float*)d_in[15];
    const float* b1      = (const float*)d_in[16];
    const float* W2      = (const float*)d_in[17];
    const float* b2      = (const float*)d_in[18];
    const float* ln_ff_g = (const float*)d_in[19];
    const float* ln_ff_b = (const float*)d_in[20];

    char* ws = (char*)d_ws;
    bf16* sb     = (bf16*)(ws);
    bf16* qb     = (bf16*)(ws + 27226112);
    bf16* samp   = (bf16*)(ws + 27226112);
    bf16* vbuf   = (bf16*)(ws + 54452224);
    bf16* ocat   = (bf16*)(ws + 81678336);
    bf16* xb16   = (bf16*)(ws + 122517504);
    bf16* Wval_t = (bf16*)(ws + 149743616);
    bf16* Wcat_t = (bf16*)(ws + 149874688);
    float* bcat  = (float*)(ws + 150071296);
    bf16* Wout_t = (bf16*)(ws + 150072832);
    bf16* W1_t   = (bf16*)(ws + 150203904);
    bf16* W2_t   = (bf16*)(ws + 150728192);
    float* outf  = (float*)d_out;

    dim3 blk(256);

    cast_qs_kernel<<<dim3((ROWS * 64 + 255) / 256), blk, 0, stream>>>(src, pos, sb, qb, ROWS * 64);
    wcast_all<<<dim3(2944), blk, 0, stream>>>(W_val, W_off, W_attn, W_out, W1, W2,
                                              b_off, b_attn,
                                              Wval_t, Wcat_t, Wout_t, W1_t, W2_t, bcat);

    // v = src @ W_val + b_val
    mfma_gemm_n<false><<<dim3(2, 416), blk, 0, stream>>>(sb, Wval_t, b_val, vbuf, ROWS, 256, 256);
    // [off | attn logits] = q @ Wcat + bcat
    mfma_gemm_n<false><<<dim3(3, 416), blk, 0, stream>>>(qb, Wcat_t, bcat, ocat, ROWS, 384, 256);
    // softmax + sampling
    sample_kernel<<<dim3(ROWS * 8 / 16), blk, 0, stream>>>(vbuf, ocat, ref, samp);
    // x = LN(samp @ W_out + b_out + sb)
    mfma_gemm_ln<<<dim3(416), dim3(512), 0, stream>>>(
        samp, Wout_t, b_out, sb, xb16, ln_sa_g, ln_sa_b, ROWS, 256);
    // out = LN(relu(x@W1+b1)@W2 + b2 + x)
    ffn_fused<<<dim3(831), blk, 0, stream>>>(
        xb16, W1_t, b1, W2_t, b2, outf, ln_ff_g, ln_ff_b, ROWS);
}

// Round 8
// 502.512 us; speedup vs baseline: 1.1183x; 1.1183x over previous
//
#include <hip/hip_runtime.h>
#include <hip/hip_bf16.h>

typedef __hip_bfloat16 bf16;
typedef short bf16x8 __attribute__((ext_vector_type(8)));
typedef float f32x4  __attribute__((ext_vector_type(4)));

#define ROWS 53176    // B * L_TOTAL
#define LTOT 13294

__device__ __forceinline__ float b2f(bf16 v) { return __bfloat162float(v); }

__device__ __forceinline__ void gl2lds16(const void* g, void* l) {
    __builtin_amdgcn_global_load_lds(
        (const __attribute__((address_space(1))) unsigned*)g,
        (__attribute__((address_space(3))) unsigned*)l, 16, 0, 0);
}

// ============ narrow MFMA GEMM: 128x128 tile, transposed-acc epilogue ============
template<bool RELU>
__global__ __launch_bounds__(256)
void mfma_gemm_n(const bf16* __restrict__ A, const bf16* __restrict__ Bt,
                 const float* __restrict__ bias, bf16* __restrict__ C,
                 int M, int N, int K)
{
    __shared__ __align__(16) short As[128 * 32];
    __shared__ __align__(16) short Bs[128 * 32];
    const int tid  = threadIdx.x;
    const int wave = tid >> 6, lane = tid & 63;
    const int m0 = blockIdx.y * 128, n0 = blockIdx.x * 128;
    const int lrow = lane >> 2, lcol = lane & 3;
    const int quad = lane >> 4;

    f32x4 acc[4][4];
#pragma unroll
    for (int i = 0; i < 4; ++i)
#pragma unroll
        for (int j = 0; j < 4; ++j) acc[i][j] = (f32x4){0.f, 0.f, 0.f, 0.f};

    const int wM = (wave >> 1) * 64, wN = (wave & 1) * 64;
    const int foff = (lane & 15) * 32 + quad * 8;

    for (int kk = 0; kk < K; kk += 32) {
#pragma unroll
        for (int q = 0; q < 2; ++q) {
            int rbase = wave * 32 + q * 16;
            int row = rbase + lrow;
            gl2lds16(A  + (size_t)(m0 + row) * K + kk + lcol * 8, &As[rbase * 32]);
            gl2lds16(Bt + (size_t)(n0 + row) * K + kk + lcol * 8, &Bs[rbase * 32]);
        }
        __syncthreads();
        bf16x8 af[4], bfr[4];
#pragma unroll
        for (int i = 0; i < 4; ++i)
            af[i] = *(const bf16x8*)&As[(wM + i * 16) * 32 + foff];
#pragma unroll
        for (int j = 0; j < 4; ++j)
            bfr[j] = *(const bf16x8*)&Bs[(wN + j * 16) * 32 + foff];
#pragma unroll
        for (int i = 0; i < 4; ++i)
#pragma unroll
            for (int j = 0; j < 4; ++j)
                acc[i][j] = __builtin_amdgcn_mfma_f32_16x16x32_bf16(bfr[j], af[i], acc[i][j], 0, 0, 0);
        __syncthreads();
    }

    float4 b4[4];
#pragma unroll
    for (int j = 0; j < 4; ++j)
        b4[j] = *(const float4*)&bias[n0 + wN + j * 16 + quad * 4];

#pragma unroll
    for (int i = 0; i < 4; ++i) {
        int gm = m0 + wM + i * 16 + (lane & 15);
        if (gm >= M) continue;
#pragma unroll
        for (int j = 0; j < 4; ++j) {
            int gn = n0 + wN + j * 16 + quad * 4;
            union { bf16 h[4]; uint2 u2; } pk;
#pragma unroll
            for (int r = 0; r < 4; ++r) {
                float v = acc[i][j][r] + ((const float*)&b4[j])[r];
                if (RELU) v = fmaxf(v, 0.f);
                pk.h[r] = __float2bfloat16(v);
            }
            *(uint2*)&C[(size_t)gm * N + gn] = pk.u2;
        }
    }
}

// ============ wide MFMA GEMM with fused LayerNorm: 128x256 tile, 512 thr ============
// out = LN( A[M,K] @ Bt[256,K]^T + bias + res(bf16) ) ; out f32 or bf16
template<typename OT>
__global__ __launch_bounds__(512)
void mfma_gemm_ln(const bf16* __restrict__ A, const bf16* __restrict__ Bt,
                  const float* __restrict__ bias, const bf16* __restrict__ res,
                  OT* __restrict__ C, const float* __restrict__ gam,
                  const float* __restrict__ bet, int M, int K)
{
    __shared__ __align__(16) short As[128 * 32];
    __shared__ __align__(16) short Bs[256 * 32];
    __shared__ float rsum[128], rsq[128];
    const int tid  = threadIdx.x;
    const int wave = tid >> 6, lane = tid & 63;
    const int m0 = blockIdx.x * 128;
    const int lrow = lane >> 2, lcol = lane & 3;
    const int quad = lane >> 4;
    if (tid < 128) { rsum[tid] = 0.f; rsq[tid] = 0.f; }

    f32x4 acc[4][4];
#pragma unroll
    for (int i = 0; i < 4; ++i)
#pragma unroll
        for (int j = 0; j < 4; ++j) acc[i][j] = (f32x4){0.f, 0.f, 0.f, 0.f};

    const int wM = (wave >> 2) * 64, wN = (wave & 3) * 64;
    const int foff = (lane & 15) * 32 + quad * 8;

    for (int kk = 0; kk < K; kk += 32) {
#pragma unroll
        for (int q = 0; q < 3; ++q) {
            int r = wave * 48 + q * 16;
            if (r < 128) {
                gl2lds16(A + (size_t)(m0 + r + lrow) * K + kk + lcol * 8, &As[r * 32]);
            } else {
                int rr = r - 128;
                gl2lds16(Bt + (size_t)(rr + lrow) * K + kk + lcol * 8, &Bs[rr * 32]);
            }
        }
        __syncthreads();
        bf16x8 af[4], bfr[4];
#pragma unroll
        for (int i = 0; i < 4; ++i)
            af[i] = *(const bf16x8*)&As[(wM + i * 16) * 32 + foff];
#pragma unroll
        for (int j = 0; j < 4; ++j)
            bfr[j] = *(const bf16x8*)&Bs[(wN + j * 16) * 32 + foff];
#pragma unroll
        for (int i = 0; i < 4; ++i)
#pragma unroll
            for (int j = 0; j < 4; ++j)
                acc[i][j] = __builtin_amdgcn_mfma_f32_16x16x32_bf16(bfr[j], af[i], acc[i][j], 0, 0, 0);
        __syncthreads();
    }

    float4 b4[4], g4[4], be4[4];
#pragma unroll
    for (int j = 0; j < 4; ++j) {
        int gn = wN + j * 16 + quad * 4;
        b4[j]  = *(const float4*)&bias[gn];
        g4[j]  = *(const float4*)&gam[gn];
        be4[j] = *(const float4*)&bet[gn];
    }

    float lsum[4], lsq[4];
#pragma unroll
    for (int i = 0; i < 4; ++i) {
        int gm = m0 + wM + i * 16 + (lane & 15);
        lsum[i] = 0.f; lsq[i] = 0.f;
#pragma unroll
        for (int j = 0; j < 4; ++j) {
            int gn = wN + j * 16 + quad * 4;
            float r4[4] = {0.f, 0.f, 0.f, 0.f};
            if (gm < M) {
                uint2 ru = *(const uint2*)&res[(size_t)gm * 256 + gn];
                const bf16* rh = (const bf16*)&ru;
#pragma unroll
                for (int r = 0; r < 4; ++r) r4[r] = b2f(rh[r]);
            }
#pragma unroll
            for (int r = 0; r < 4; ++r) {
                float v = acc[i][j][r] + ((const float*)&b4[j])[r] + r4[r];
                acc[i][j][r] = v;
                lsum[i] += v;
                lsq[i]  += v * v;
            }
        }
#pragma unroll
        for (int mask = 16; mask <= 32; mask <<= 1) {
            lsum[i] += __shfl_xor(lsum[i], mask);
            lsq[i]  += __shfl_xor(lsq[i], mask);
        }
    }
    if (quad == 0) {
#pragma unroll
        for (int i = 0; i < 4; ++i) {
            atomicAdd(&rsum[wM + i * 16 + (lane & 15)], lsum[i]);
            atomicAdd(&rsq [wM + i * 16 + (lane & 15)], lsq[i]);
        }
    }
    __syncthreads();

#pragma unroll
    for (int i = 0; i < 4; ++i) {
        int lr = wM + i * 16 + (lane & 15);
        int gm = m0 + lr;
        if (gm >= M) continue;
        float mean = rsum[lr] * (1.f / 256.f);
        float var  = rsq[lr] * (1.f / 256.f) - mean * mean;
        float rstd = rsqrtf(fmaxf(var, 0.f) + 1e-5f);
#pragma unroll
        for (int j = 0; j < 4; ++j) {
            int gn = wN + j * 16 + quad * 4;
            if constexpr (sizeof(OT) == 2) {
                union { bf16 h[4]; uint2 u2; } pk;
#pragma unroll
                for (int r = 0; r < 4; ++r)
                    pk.h[r] = __float2bfloat16((acc[i][j][r] - mean) * rstd *
                              ((const float*)&g4[j])[r] + ((const float*)&be4[j])[r]);
                *(uint2*)&((bf16*)C)[(size_t)gm * 256 + gn] = pk.u2;
            } else {
                float4 o;
#pragma unroll
                for (int r = 0; r < 4; ++r)
                    ((float*)&o)[r] = (acc[i][j][r] - mean) * rstd *
                              ((const float*)&g4[j])[r] + ((const float*)&be4[j])[r];
                *(float4*)&((float*)C)[(size_t)gm * 256 + gn] = o;
            }
        }
    }
}

// ============ casts ============
__global__ void cast_qs_kernel(const float* __restrict__ s, const float* __restrict__ p,
                               bf16* __restrict__ sb, bf16* __restrict__ qb, int n4)
{
    int i = blockIdx.x * 256 + threadIdx.x;
    if (i >= n4) return;
    float4 sv = ((const float4*)s)[i];
    float4 pv = ((const float4*)p)[i];
    union { bf16 h[4]; uint2 u; } a, b;
    a.h[0] = __float2bfloat16(sv.x); a.h[1] = __float2bfloat16(sv.y);
    a.h[2] = __float2bfloat16(sv.z); a.h[3] = __float2bfloat16(sv.w);
    b.h[0] = __float2bfloat16(sv.x + pv.x); b.h[1] = __float2bfloat16(sv.y + pv.y);
    b.h[2] = __float2bfloat16(sv.z + pv.z); b.h[3] = __float2bfloat16(sv.w + pv.w);
    ((uint2*)sb)[i] = a.u;
    ((uint2*)qb)[i] = b.u;
}

__global__ void wcast_all(const float* __restrict__ Wval, const float* __restrict__ Woff,
                          const float* __restrict__ Wattn, const float* __restrict__ Wout,
                          const float* __restrict__ W1, const float* __restrict__ W2,
                          const float* __restrict__ boff, const float* __restrict__ battn,
                          bf16* __restrict__ Wval_t, bf16* __restrict__ Wcat_t,
                          bf16* __restrict__ Wout_t, bf16* __restrict__ W1_t,
                          bf16* __restrict__ W2_t, float* __restrict__ bcat)
{
    int e = blockIdx.x * 256 + threadIdx.x;
    if (e < 384) bcat[e] = (e < 256) ? boff[e] : battn[e - 256];
    if (e < 65536) {
        int n = e >> 8, k = e & 255;
        Wval_t[e] = __float2bfloat16(Wval[k * 256 + n]);
    } else if (e < 163840) {
        int i = e - 65536; int n = i >> 8, k = i & 255;
        float w = (n < 256) ? Woff[k * 256 + n] : Wattn[k * 128 + (n - 256)];
        Wcat_t[i] = __float2bfloat16(w);
    } else if (e < 229376) {
        int i = e - 163840; int n = i >> 8, k = i & 255;
        Wout_t[i] = __float2bfloat16(Wout[k * 256 + n]);
    } else if (e < 491520) {
        int i = e - 229376; int n = i >> 8, k = i & 255;
        W1_t[i] = __float2bfloat16(W1[k * 1024 + n]);
    } else if (e < 753664) {
        int i = e - 491520; int n = i >> 10, k = i & 1023;
        W2_t[i] = __float2bfloat16(W2[k * 256 + n]);
    }
}

// ============ deformable sampling + fused softmax (16-lane groups) ============
__global__ __launch_bounds__(256)
void sample_kernel(const bf16* __restrict__ v, const bf16* __restrict__ ocat,
                   const float* __restrict__ ref, bf16* __restrict__ samp)
{
    __shared__ int4 tab[16][33];
    const int tid = threadIdx.x;
    const int grp = tid >> 4, lane = tid & 15;
    const int gidx = blockIdx.x * 16 + grp;
    const int h = gidx & 7, bq = gidx >> 3, b = bq / LTOT;

    {   // phase A: point p = lane; softmax over 16 lanes
        const int p = lane, l = p >> 2, pp = p & 3;
        const int W = (l == 0) ? 100 : (l == 1) ? 50 : (l == 2) ? 25 : 13;
        const int S = (l == 0) ? 0 : (l == 1) ? 10000 : (l == 2) ? 12500 : 13125;
        const float fW = (float)W;
        float rx = ref[(size_t)bq * 8 + l * 2 + 0];
        float ry = ref[(size_t)bq * 8 + l * 2 + 1];
        const bf16* ob = ocat + (size_t)bq * 384;
        float ox = b2f(ob[h * 32 + l * 8 + pp * 2 + 0]);
        float oy = b2f(ob[h * 32 + l * 8 + pp * 2 + 1]);
        float lg = b2f(ob[256 + h * 16 + p]);
        float m = lg;
#pragma unroll
        for (int mask = 1; mask <= 8; mask <<= 1) m = fmaxf(m, __shfl_xor(m, mask));
        float ev = __expf(lg - m);
        float s = ev;
#pragma unroll
        for (int mask = 1; mask <= 8; mask <<= 1) s += __shfl_xor(s, mask);
        float wgt = ev / s;

        // (rx + ox/W)*W - 0.5 == rx*W + ox - 0.5 (up to ~1 ulp)
        float x = fmaf(rx, fW, ox - 0.5f);
        float y = fmaf(ry, fW, oy - 0.5f);   // H == W at every level
        float x0f = floorf(x), y0f = floorf(y);
        float lx = x - x0f, ly = y - y0f;
        int x0 = (int)x0f, y0 = (int)y0f;
        float tw[4] = {(1.f - lx) * (1.f - ly), lx * (1.f - ly),
                       (1.f - lx) * ly,         lx * ly};
        const int base = (b * LTOT + S) * 512 + h * 64;
        int  o[4]; float w[4];
#pragma unroll
        for (int t = 0; t < 4; ++t) {
            int xi = x0 + (t & 1), yi = y0 + (t >> 1);
            bool ok = (xi >= 0) & (xi < W) & (yi >= 0) & (yi < W);
            o[t] = ok ? base + (yi * W + xi) * 512 : 0;
            w[t] = ok ? wgt * tw[t] : 0.f;
        }
        tab[grp][p * 2 + 0] = make_int4(o[0], __float_as_int(w[0]), o[1], __float_as_int(w[1]));
        tab[grp][p * 2 + 1] = make_int4(o[2], __float_as_int(w[2]), o[3], __float_as_int(w[3]));
    }
    __syncthreads();

    const int lofs = lane * 4;
    const char* vc = (const char*)v;
    float a0 = 0.f, a1 = 0.f;
#pragma unroll 4
    for (int e2 = 0; e2 < 32; ++e2) {
        int4 q = tab[grp][e2];
        unsigned u0 = *(const unsigned*)(vc + (size_t)(unsigned)(q.x + lofs));
        unsigned u1 = *(const unsigned*)(vc + (size_t)(unsigned)(q.z + lofs));
        float w0 = __int_as_float(q.y), w1 = __int_as_float(q.w);
        a0 += w0 * __uint_as_float(u0 << 16);
        a1 += w0 * __uint_as_float(u0);   // low-16 mantissa noise, within budget
        a0 += w1 * __uint_as_float(u1 << 16);
        a1 += w1 * __uint_as_float(u1);
    }
    union { struct { bf16 a, b; } h2; unsigned u; } r;
    r.h2.a = __float2bfloat16(a0);
    r.h2.b = __float2bfloat16(a1);
    *(unsigned*)((char*)samp + (size_t)gidx * 64 + lane * 4) = r.u;
}

extern "C" void kernel_launch(void* const* d_in, const int* in_sizes, int n_in,
                              void* d_out, int out_size, void* d_ws, size_t ws_size,
                              hipStream_t stream)
{
    const float* src     = (const float*)d_in[0];
    const float* pos     = (const float*)d_in[1];
    const float* ref     = (const float*)d_in[2];
    const float* W_off   = (const float*)d_in[5];
    const float* b_off   = (const float*)d_in[6];
    const float* W_attn  = (const float*)d_in[7];
    const float* b_attn  = (const float*)d_in[8];
    const float* W_val   = (const float*)d_in[9];
    const float* b_val   = (const float*)d_in[10];
    const float* W_out   = (const float*)d_in[11];
    const float* b_out   = (const float*)d_in[12];
    const float* ln_sa_g = (const float*)d_in[13];
    const float* ln_sa_b = (const float*)d_in[14];
    const float* W1      = (const float*)d_in[15];
    const float* b1      = (const float*)d_in[16];
    const float* W2      = (const float*)d_in[17];
    const float* b2      = (const float*)d_in[18];
    const float* ln_ff_g = (const float*)d_in[19];
    const float* ln_ff_b = (const float*)d_in[20];

    char* ws = (char*)d_ws;
    // ws layout:
    //   sb   [0, 27226112)          cast -> G1(A), G6(residual)
    //   qb   [27226112, 54452224)   cast -> G23;  then samp (sample -> G6)
    //   vbuf [54452224, 81678336)   G1 -> sample
    //   ocat [81678336, 122517504)  G23 -> sample
    //   xb16 [122517504, 149743616) G6 -> G8, G9(residual)
    //   wts  [149743616, 151252480)
    //   hbuf [0, 108904448)         G8 -> G9 (overlaps sb/qb/vbuf/ocat-head, all dead)
    bf16* sb     = (bf16*)(ws);
    bf16* qb     = (bf16*)(ws + 27226112);
    bf16* samp   = (bf16*)(ws + 27226112);
    bf16* vbuf   = (bf16*)(ws + 54452224);
    bf16* ocat   = (bf16*)(ws + 81678336);
    bf16* xb16   = (bf16*)(ws + 122517504);
    bf16* hbuf   = (bf16*)(ws);
    bf16* Wval_t = (bf16*)(ws + 149743616);
    bf16* Wcat_t = (bf16*)(ws + 149874688);
    float* bcat  = (float*)(ws + 150071296);
    bf16* Wout_t = (bf16*)(ws + 150072832);
    bf16* W1_t   = (bf16*)(ws + 150203904);
    bf16* W2_t   = (bf16*)(ws + 150728192);
    float* outf  = (float*)d_out;

    dim3 blk(256);

    cast_qs_kernel<<<dim3((ROWS * 64 + 255) / 256), blk, 0, stream>>>(src, pos, sb, qb, ROWS * 64);
    wcast_all<<<dim3(2944), blk, 0, stream>>>(W_val, W_off, W_attn, W_out, W1, W2,
                                              b_off, b_attn,
                                              Wval_t, Wcat_t, Wout_t, W1_t, W2_t, bcat);

    // v = src @ W_val + b_val
    mfma_gemm_n<false><<<dim3(2, 416), blk, 0, stream>>>(sb, Wval_t, b_val, vbuf, ROWS, 256, 256);
    // [off | attn logits] = q @ Wcat + bcat
    mfma_gemm_n<false><<<dim3(3, 416), blk, 0, stream>>>(qb, Wcat_t, bcat, ocat, ROWS, 384, 256);
    // softmax + sampling
    sample_kernel<<<dim3(ROWS * 8 / 16), blk, 0, stream>>>(vbuf, ocat, ref, samp);
    // x = LN(samp @ W_out + b_out + sb)
    mfma_gemm_ln<bf16><<<dim3(416), dim3(512), 0, stream>>>(
        samp, Wout_t, b_out, sb, xb16, ln_sa_g, ln_sa_b, ROWS, 256);
    // h = relu(x @ W1 + b1)
    mfma_gemm_n<true><<<dim3(8, 416), blk, 0, stream>>>(xb16, W1_t, b1, hbuf, ROWS, 1024, 256);
    // out = LN(h @ W2 + b2 + x)
    mfma_gemm_ln<float><<<dim3(416), dim3(512), 0, stream>>>(
        hbuf, W2_t, b2, xb16, outf, ln_ff_g, ln_ff_b, ROWS, 1024);
}